// Round 1
// baseline (1817.552 us; speedup 1.0000x reference)
//
#include <hip/hip_runtime.h>
#include <hip/hip_bf16.h>

#define H 1536
#define I 4096
#define T 2048
#define E_SH 2
#define E_RT 6
#define E_TOT 8

typedef __hip_bfloat16 bf16;
typedef __attribute__((ext_vector_type(8))) short bf16x8;
typedef __attribute__((ext_vector_type(4))) float f32x4;

// async global->LDS, 16B per lane. LDS dest is wave-uniform base + lane*16;
// we arrange per-lane pointers to exactly match that form.
__device__ __forceinline__ void gld16(const void* g, void* l) {
  __builtin_amdgcn_global_load_lds(
      (const __attribute__((address_space(1))) unsigned int*)(unsigned long long)g,
      (__attribute__((address_space(3))) unsigned int*)(unsigned int)(unsigned long long)l,
      16, 0, 0);
}

// ---------------- x fp32 -> bf16 ----------------
__global__ __launch_bounds__(256) void cvt_x(const float* __restrict__ x,
                                             bf16* __restrict__ xb, int n) {
  int i = (blockIdx.x * 256 + threadIdx.x) * 4;
  if (i + 3 < n) {
    float4 v = *(const float4*)(x + i);
    xb[i + 0] = __float2bfloat16(v.x);
    xb[i + 1] = __float2bfloat16(v.y);
    xb[i + 2] = __float2bfloat16(v.z);
    xb[i + 3] = __float2bfloat16(v.w);
  }
}

// ---------------- router: softmax top-2 renorm -> scale[T][E_TOT] ----------------
__global__ __launch_bounds__(256) void router(const float* __restrict__ x,
                                              const float* __restrict__ Wr,
                                              const float* __restrict__ rb,
                                              float* __restrict__ scale) {
  int t = blockIdx.x * 4 + (threadIdx.x >> 6);
  int lane = threadIdx.x & 63;
  float acc[E_RT] = {0.f, 0.f, 0.f, 0.f, 0.f, 0.f};
  for (int k = lane; k < H; k += 64) {
    float xv = x[(size_t)t * H + k];
#pragma unroll
    for (int e = 0; e < E_RT; ++e) acc[e] += xv * Wr[k * E_RT + e];
  }
#pragma unroll
  for (int e = 0; e < E_RT; ++e)
#pragma unroll
    for (int off = 32; off > 0; off >>= 1) acc[e] += __shfl_down(acc[e], off);
  if (lane == 0) {
    float l[E_RT];
#pragma unroll
    for (int e = 0; e < E_RT; ++e) l[e] = acc[e] + rb[e];
    int i1 = 0;
#pragma unroll
    for (int e = 1; e < E_RT; ++e) if (l[e] > l[i1]) i1 = e;
    int i2 = -1;
#pragma unroll
    for (int e = 0; e < E_RT; ++e)
      if (e != i1 && (i2 < 0 || l[e] > l[i2])) i2 = e;
    float w1 = 1.f / (1.f + __expf(l[i2] - l[i1]));  // = p1/(p1+p2)
    float w2 = 1.f - w1;
    float* s = scale + (size_t)t * E_TOT;
    s[0] = 0.5f; s[1] = 0.5f;  // shared experts: sum/2
#pragma unroll
    for (int e = 0; e < E_RT; ++e) s[2 + e] = 0.f;
    s[2 + i1] = w1;
    s[2 + i2] = w2;
  }
}

// ---------------- fp32 [R,C] -> bf16 [C,R] tiled transpose-convert ----------------
__global__ __launch_bounds__(256) void transpose_cvt(const float* __restrict__ in,
                                                     bf16* __restrict__ out,
                                                     int R, int C) {
  __shared__ bf16 tile[64][66];
  size_t bo = (size_t)blockIdx.z * R * C;
  in += bo; out += bo;
  int c0 = blockIdx.x * 64, r0 = blockIdx.y * 64;
  int tx = threadIdx.x & 63, ty = threadIdx.x >> 6;
#pragma unroll
  for (int i = 0; i < 16; ++i) {
    int r = ty * 16 + i;
    tile[tx][r] = __float2bfloat16(in[(size_t)(r0 + r) * C + c0 + tx]);
  }
  __syncthreads();
#pragma unroll
  for (int i = 0; i < 16; ++i) {
    int c = ty * 16 + i;
    out[(size_t)(c0 + c) * R + r0 + tx] = tile[c][tx];
  }
}

// ---------------- fused gate+up GEMM + silu*u*scale -> h bf16 ----------------
// A = xb [T,H], B^T = WgT/WuT [e][I,H], out h [e][T,I]
__global__ __launch_bounds__(256) void gemm_gateup(const bf16* __restrict__ xb,
                                                   const bf16* __restrict__ WgT,
                                                   const bf16* __restrict__ WuT,
                                                   const float* __restrict__ scale,
                                                   bf16* __restrict__ hbuf) {
  __shared__ bf16 As[128 * 32];
  __shared__ bf16 Bg[128 * 32];
  __shared__ bf16 Bu[128 * 32];
  const int e = blockIdx.z;
  const int n0 = blockIdx.x * 128;  // I
  const int m0 = blockIdx.y * 128;  // T
  const int tid = threadIdx.x;
  const int wave = tid >> 6, lane = tid & 63;
  const int wr = wave >> 1, wc = wave & 1;
  const int quad = lane >> 4, l15 = lane & 15;

  const bf16* Ag = xb + (size_t)m0 * H;
  const bf16* Bgg = WgT + (size_t)e * I * H + (size_t)n0 * H;
  const bf16* Bug = WuT + (size_t)e * I * H + (size_t)n0 * H;

  f32x4 accg[4][4], accu[4][4];
  f32x4 zero = {0.f, 0.f, 0.f, 0.f};
#pragma unroll
  for (int j = 0; j < 4; ++j)
#pragma unroll
    for (int i = 0; i < 4; ++i) { accg[j][i] = zero; accu[j][i] = zero; }

  for (int kt = 0; kt < H; kt += 32) {
    __syncthreads();  // all waves done reading LDS from prev iter
#pragma unroll
    for (int it = 0; it < 2; ++it) {
      int chunk = (wave * 2 + it) * 64 + lane;
      int row = chunk >> 2, kc = chunk & 3;
      gld16(Ag + (size_t)row * H + kt + kc * 8, As + chunk * 8);
      gld16(Bgg + (size_t)row * H + kt + kc * 8, Bg + chunk * 8);
      gld16(Bug + (size_t)row * H + kt + kc * 8, Bu + chunk * 8);
    }
    __syncthreads();  // drains vmcnt: staging visible
    bf16x8 a[4];
#pragma unroll
    for (int i = 0; i < 4; ++i)
      a[i] = *(const bf16x8*)(As + (wr * 64 + i * 16 + l15) * 32 + quad * 8);
#pragma unroll
    for (int j = 0; j < 4; ++j) {
      bf16x8 bg = *(const bf16x8*)(Bg + (wc * 64 + j * 16 + l15) * 32 + quad * 8);
      bf16x8 bu = *(const bf16x8*)(Bu + (wc * 64 + j * 16 + l15) * 32 + quad * 8);
#pragma unroll
      for (int i = 0; i < 4; ++i) {
        accg[j][i] = __builtin_amdgcn_mfma_f32_16x16x32_bf16(a[i], bg, accg[j][i], 0, 0, 0);
        accu[j][i] = __builtin_amdgcn_mfma_f32_16x16x32_bf16(a[i], bu, accu[j][i], 0, 0, 0);
      }
    }
  }
  // epilogue: h = silu(g)*u*scale(t,e)  (C/D: col=lane&15, row=quad*4+r)
  bf16* hp = hbuf + (size_t)e * T * I;
  float sc[4][4];
#pragma unroll
  for (int i = 0; i < 4; ++i)
#pragma unroll
    for (int r = 0; r < 4; ++r) {
      int trow = m0 + wr * 64 + i * 16 + quad * 4 + r;
      sc[i][r] = scale[(size_t)trow * E_TOT + e];
    }
#pragma unroll
  for (int j = 0; j < 4; ++j)
#pragma unroll
    for (int i = 0; i < 4; ++i)
#pragma unroll
      for (int r = 0; r < 4; ++r) {
        int trow = m0 + wr * 64 + i * 16 + quad * 4 + r;
        int ncol = n0 + wc * 64 + j * 16 + l15;
        float g = accg[j][i][r], u = accu[j][i][r];
        float hv = (g / (1.f + __expf(-g))) * u * sc[i][r];
        hp[(size_t)trow * I + ncol] = __float2bfloat16(hv);
      }
}

// ---------------- down GEMM: out += h_e @ Wd_e (split-K over experts, atomics) ----
// A = hbuf [e][T,I], B^T = WdT [e][H,I], out fp32 [T,H]
__global__ __launch_bounds__(256) void gemm_down(const bf16* __restrict__ hbuf,
                                                 const bf16* __restrict__ WdT,
                                                 float* __restrict__ out) {
  __shared__ bf16 As[128 * 32];
  __shared__ bf16 Bs[128 * 32];
  const int e = blockIdx.z;
  const int n0 = blockIdx.x * 128;  // H
  const int m0 = blockIdx.y * 128;  // T
  const int tid = threadIdx.x;
  const int wave = tid >> 6, lane = tid & 63;
  const int wr = wave >> 1, wc = wave & 1;
  const int quad = lane >> 4, l15 = lane & 15;

  const bf16* Ag = hbuf + (size_t)e * T * I + (size_t)m0 * I;
  const bf16* Bgp = WdT + (size_t)e * H * I + (size_t)n0 * I;

  f32x4 acc[4][4];
  f32x4 zero = {0.f, 0.f, 0.f, 0.f};
#pragma unroll
  for (int j = 0; j < 4; ++j)
#pragma unroll
    for (int i = 0; i < 4; ++i) acc[j][i] = zero;

  for (int kt = 0; kt < I; kt += 32) {
    __syncthreads();
#pragma unroll
    for (int it = 0; it < 2; ++it) {
      int chunk = (wave * 2 + it) * 64 + lane;
      int row = chunk >> 2, kc = chunk & 3;
      gld16(Ag + (size_t)row * I + kt + kc * 8, As + chunk * 8);
      gld16(Bgp + (size_t)row * I + kt + kc * 8, Bs + chunk * 8);
    }
    __syncthreads();
    bf16x8 a[4];
#pragma unroll
    for (int i = 0; i < 4; ++i)
      a[i] = *(const bf16x8*)(As + (wr * 64 + i * 16 + l15) * 32 + quad * 8);
#pragma unroll
    for (int j = 0; j < 4; ++j) {
      bf16x8 b = *(const bf16x8*)(Bs + (wc * 64 + j * 16 + l15) * 32 + quad * 8);
#pragma unroll
      for (int i = 0; i < 4; ++i)
        acc[j][i] = __builtin_amdgcn_mfma_f32_16x16x32_bf16(a[i], b, acc[j][i], 0, 0, 0);
    }
  }
#pragma unroll
  for (int j = 0; j < 4; ++j)
#pragma unroll
    for (int i = 0; i < 4; ++i)
#pragma unroll
      for (int r = 0; r < 4; ++r) {
        int trow = m0 + wr * 64 + i * 16 + quad * 4 + r;
        int ncol = n0 + wc * 64 + j * 16 + l15;
        atomicAdd(&out[(size_t)trow * H + ncol], acc[j][i][r]);
      }
}

extern "C" void kernel_launch(void* const* d_in, const int* in_sizes, int n_in,
                              void* d_out, int out_size, void* d_ws, size_t ws_size,
                              hipStream_t stream) {
  const float* x    = (const float*)d_in[0];
  const float* Wg_s = (const float*)d_in[1];
  const float* Wu_s = (const float*)d_in[2];
  const float* Wd_s = (const float*)d_in[3];
  const float* Wg_r = (const float*)d_in[4];
  const float* Wu_r = (const float*)d_in[5];
  const float* Wd_r = (const float*)d_in[6];
  const float* Wr   = (const float*)d_in[7];
  const float* rb   = (const float*)d_in[8];
  float* out = (float*)d_out;

  char* p = (char*)d_ws;
  bf16* xb  = (bf16*)p;  p += (size_t)T * H * 2;
  bf16* WgT = (bf16*)p;  p += (size_t)E_TOT * I * H * 2;
  bf16* WuT = (bf16*)p;  p += (size_t)E_TOT * I * H * 2;
  bf16* hbuf = (bf16*)p; p += (size_t)E_TOT * T * I * 2;
  float* scale = (float*)p;  p += (size_t)T * E_TOT * 4;
  bf16* WdT = WgT;  // reuse: Wd transpose happens after gate/up GEMM is done with WgT

  hipMemsetAsync(d_out, 0, (size_t)T * H * 4, stream);
  cvt_x<<<(T * H) / 1024, 256, 0, stream>>>(x, xb, T * H);
  router<<<T / 4, 256, 0, stream>>>(x, Wr, rb, scale);

  // gate/up: [H,I] -> [I,H] bf16
  transpose_cvt<<<dim3(I / 64, H / 64, E_SH), 256, 0, stream>>>(Wg_s, WgT, H, I);
  transpose_cvt<<<dim3(I / 64, H / 64, E_RT), 256, 0, stream>>>(Wg_r, WgT + (size_t)E_SH * I * H, H, I);
  transpose_cvt<<<dim3(I / 64, H / 64, E_SH), 256, 0, stream>>>(Wu_s, WuT, H, I);
  transpose_cvt<<<dim3(I / 64, H / 64, E_RT), 256, 0, stream>>>(Wu_r, WuT + (size_t)E_SH * I * H, H, I);

  gemm_gateup<<<dim3(I / 128, T / 128, E_TOT), 256, 0, stream>>>(xb, WgT, WuT, scale, hbuf);

  // down: [I,H] -> [H,I] bf16 (into WgT region, safe: stream-ordered)
  transpose_cvt<<<dim3(H / 64, I / 64, E_SH), 256, 0, stream>>>(Wd_s, WdT, I, H);
  transpose_cvt<<<dim3(H / 64, I / 64, E_RT), 256, 0, stream>>>(Wd_r, WdT + (size_t)E_SH * H * I, I, H);

  gemm_down<<<dim3(H / 128, T / 128, E_TOT), 256, 0, stream>>>(hbuf, WdT, out);
}

// Round 2
// 1396.238 us; speedup vs baseline: 1.3017x; 1.3017x over previous
//
#include <hip/hip_runtime.h>
#include <hip/hip_bf16.h>

#define H 1536
#define I 4096
#define T 2048
#define E_SH 2
#define E_RT 6
#define E_TOT 8
// h-buffer capacity in rows: 2 shared experts (T each) + 2T routed rows total,
// plus per-routed-expert tile padding to 128.
#define HROWS (4 * T + E_RT * 128)

typedef __hip_bfloat16 bf16;
typedef __attribute__((ext_vector_type(8))) short bf16x8;
typedef __attribute__((ext_vector_type(4))) float f32x4;

// async global->LDS, 16B per lane. LDS dest must be wave-uniform base + lane*16;
// the GLOBAL address may be arbitrary per-lane (gather is fine).
__device__ __forceinline__ void gld16(const void* g, void* l) {
  __builtin_amdgcn_global_load_lds(
      (const __attribute__((address_space(1))) unsigned int*)(unsigned long long)g,
      (__attribute__((address_space(3))) unsigned int*)(unsigned int)(unsigned long long)l,
      16, 0, 0);
}

// ---------------- x fp32 -> bf16 ----------------
__global__ __launch_bounds__(256) void cvt_x(const float* __restrict__ x,
                                             bf16* __restrict__ xb, int n) {
  int i = (blockIdx.x * 256 + threadIdx.x) * 4;
  if (i + 3 < n) {
    float4 v = *(const float4*)(x + i);
    xb[i + 0] = __float2bfloat16(v.x);
    xb[i + 1] = __float2bfloat16(v.y);
    xb[i + 2] = __float2bfloat16(v.z);
    xb[i + 3] = __float2bfloat16(v.w);
  }
}

// ---------------- router: top-2 renorm -> per-expert token lists ----------------
// experts 0,1 = shared (identity list, weight 1; the /2 is folded into Wd_s).
// experts 2..7 = routed, appended via atomic counter (order-independent result).
__global__ __launch_bounds__(256) void router(const float* __restrict__ x,
                                              const float* __restrict__ Wr,
                                              const float* __restrict__ rb,
                                              int* __restrict__ tok_list,
                                              float* __restrict__ wt_list,
                                              int* __restrict__ cnt_r) {
  int t = blockIdx.x * 4 + (threadIdx.x >> 6);
  int lane = threadIdx.x & 63;
  float acc[E_RT] = {0.f, 0.f, 0.f, 0.f, 0.f, 0.f};
  for (int k = lane; k < H; k += 64) {
    float xv = x[(size_t)t * H + k];
#pragma unroll
    for (int e = 0; e < E_RT; ++e) acc[e] += xv * Wr[k * E_RT + e];
  }
#pragma unroll
  for (int e = 0; e < E_RT; ++e)
#pragma unroll
    for (int off = 32; off > 0; off >>= 1) acc[e] += __shfl_down(acc[e], off);
  if (lane == 0) {
    float l[E_RT];
#pragma unroll
    for (int e = 0; e < E_RT; ++e) l[e] = acc[e] + rb[e];
    int i1 = 0;
#pragma unroll
    for (int e = 1; e < E_RT; ++e) if (l[e] > l[i1]) i1 = e;
    int i2 = -1;
#pragma unroll
    for (int e = 0; e < E_RT; ++e)
      if (e != i1 && (i2 < 0 || l[e] > l[i2])) i2 = e;
    float w1 = 1.f / (1.f + __expf(l[i2] - l[i1]));  // = p1/(p1+p2)
    float w2 = 1.f - w1;
    // shared identity lists
    tok_list[0 * T + t] = t; wt_list[0 * T + t] = 1.f;
    tok_list[1 * T + t] = t; wt_list[1 * T + t] = 1.f;
    int s1 = atomicAdd(&cnt_r[i1], 1);
    tok_list[(2 + i1) * T + s1] = t; wt_list[(2 + i1) * T + s1] = w1;
    int s2 = atomicAdd(&cnt_r[i2], 1);
    tok_list[(2 + i2) * T + s2] = t; wt_list[(2 + i2) * T + s2] = w2;
  }
}

// ---------------- prefix: per-expert h-row base (tile-padded) + counts ----------
__global__ void prefix(const int* __restrict__ cnt_r,
                       int* __restrict__ base, int* __restrict__ cnt_all) {
  if (threadIdx.x == 0) {
    base[0] = 0;     cnt_all[0] = T;
    base[1] = T;     cnt_all[1] = T;
    int b = 2 * T;
    for (int e = 0; e < E_RT; ++e) {
      base[2 + e] = b;
      int c = cnt_r[e];
      cnt_all[2 + e] = c;
      b += (c + 127) & ~127;
    }
  }
}

// ---------------- fp32 [R,C] -> bf16 [C,R] tiled transpose-convert (xscale) -----
__global__ __launch_bounds__(256) void transpose_cvt(const float* __restrict__ in,
                                                     bf16* __restrict__ out,
                                                     int R, int C, float scl) {
  __shared__ bf16 tile[64][66];
  size_t bo = (size_t)blockIdx.z * R * C;
  in += bo; out += bo;
  int c0 = blockIdx.x * 64, r0 = blockIdx.y * 64;
  int tx = threadIdx.x & 63, ty = threadIdx.x >> 6;
#pragma unroll
  for (int i = 0; i < 16; ++i) {
    int r = ty * 16 + i;
    tile[tx][r] = __float2bfloat16(scl * in[(size_t)(r0 + r) * C + c0 + tx]);
  }
  __syncthreads();
#pragma unroll
  for (int i = 0; i < 16; ++i) {
    int c = ty * 16 + i;
    out[(size_t)(c0 + c) * R + r0 + tx] = tile[c][tx];
  }
}

// ---------------- gathered fused gate+up GEMM + silu*u*wt -> h bf16 -------------
// A = xb rows gathered via tok_list[e]; B^T = WgT/WuT [e][I,H]; h slot-compact.
__global__ __launch_bounds__(256) void gemm_gateup(const bf16* __restrict__ xb,
                                                   const bf16* __restrict__ WgT,
                                                   const bf16* __restrict__ WuT,
                                                   const int* __restrict__ tok_list,
                                                   const float* __restrict__ wt_list,
                                                   const int* __restrict__ cnt_all,
                                                   const int* __restrict__ base,
                                                   bf16* __restrict__ hbuf) {
  const int e = blockIdx.z;
  const int cnt = cnt_all[e];
  const int m0 = blockIdx.y * 128;
  if (m0 >= cnt) return;  // uniform early-exit (inactive tile)
  __shared__ bf16 As[128 * 32];
  __shared__ bf16 Bg[128 * 32];
  __shared__ bf16 Bu[128 * 32];
  __shared__ int toks[128];
  __shared__ float wts[128];
  const int n0 = blockIdx.x * 128;  // I
  const int tid = threadIdx.x;
  const int wave = tid >> 6, lane = tid & 63;
  const int wr = wave >> 1, wc = wave & 1;
  const int quad = lane >> 4, l15 = lane & 15;

  if (tid < 128) {
    int s = m0 + tid;
    bool v = s < cnt;
    toks[tid] = v ? tok_list[e * T + s] : 0;
    wts[tid] = v ? wt_list[e * T + s] : 0.f;
  }
  __syncthreads();

  // per-lane staging pointers (row indices constant across K)
  const int c0 = (wave * 2 + 0) * 64 + lane;
  const int c1 = (wave * 2 + 1) * 64 + lane;
  const bf16* a0 = xb + (size_t)toks[c0 >> 2] * H + (c0 & 3) * 8;
  const bf16* a1 = xb + (size_t)toks[c1 >> 2] * H + (c1 & 3) * 8;
  const bf16* Bge = WgT + (size_t)e * I * H + (size_t)n0 * H;
  const bf16* Bue = WuT + (size_t)e * I * H + (size_t)n0 * H;
  const bf16* bg0 = Bge + (size_t)(c0 >> 2) * H + (c0 & 3) * 8;
  const bf16* bg1 = Bge + (size_t)(c1 >> 2) * H + (c1 & 3) * 8;
  const bf16* bu0 = Bue + (size_t)(c0 >> 2) * H + (c0 & 3) * 8;
  const bf16* bu1 = Bue + (size_t)(c1 >> 2) * H + (c1 & 3) * 8;

  f32x4 accg[4][4], accu[4][4];
  f32x4 zero = {0.f, 0.f, 0.f, 0.f};
#pragma unroll
  for (int j = 0; j < 4; ++j)
#pragma unroll
    for (int i = 0; i < 4; ++i) { accg[j][i] = zero; accu[j][i] = zero; }

  for (int kt = 0; kt < H; kt += 32) {
    __syncthreads();
    gld16(a0 + kt, As + c0 * 8);
    gld16(a1 + kt, As + c1 * 8);
    gld16(bg0 + kt, Bg + c0 * 8);
    gld16(bg1 + kt, Bg + c1 * 8);
    gld16(bu0 + kt, Bu + c0 * 8);
    gld16(bu1 + kt, Bu + c1 * 8);
    __syncthreads();
    bf16x8 a[4];
#pragma unroll
    for (int i = 0; i < 4; ++i)
      a[i] = *(const bf16x8*)(As + (wr * 64 + i * 16 + l15) * 32 + quad * 8);
#pragma unroll
    for (int j = 0; j < 4; ++j) {
      bf16x8 bg = *(const bf16x8*)(Bg + (wc * 64 + j * 16 + l15) * 32 + quad * 8);
      bf16x8 bu = *(const bf16x8*)(Bu + (wc * 64 + j * 16 + l15) * 32 + quad * 8);
#pragma unroll
      for (int i = 0; i < 4; ++i) {
        accg[j][i] = __builtin_amdgcn_mfma_f32_16x16x32_bf16(a[i], bg, accg[j][i], 0, 0, 0);
        accu[j][i] = __builtin_amdgcn_mfma_f32_16x16x32_bf16(a[i], bu, accu[j][i], 0, 0, 0);
      }
    }
  }
  // epilogue: h = silu(g)*u*wt   (C/D: col=lane&15, row=quad*4+r)
  bf16* hp = hbuf + (size_t)(base[e] + m0) * I;
#pragma unroll
  for (int j = 0; j < 4; ++j)
#pragma unroll
    for (int i = 0; i < 4; ++i)
#pragma unroll
      for (int r = 0; r < 4; ++r) {
        int lrow = wr * 64 + i * 16 + quad * 4 + r;
        int ncol = n0 + wc * 64 + j * 16 + l15;
        float g = accg[j][i][r], u = accu[j][i][r];
        float hv = (g / (1.f + __expf(-g))) * u * wts[lrow];
        hp[(size_t)lrow * I + ncol] = __float2bfloat16(hv);
      }
}

// ---------------- down GEMM: scatter-add h_e @ Wd_e into out -------------------
// A = hbuf slot rows (contiguous), B^T = WdT [e][H,I], out fp32 [T,H] via atomics
__global__ __launch_bounds__(256) void gemm_down(const bf16* __restrict__ hbuf,
                                                 const bf16* __restrict__ WdT,
                                                 const int* __restrict__ tok_list,
                                                 const int* __restrict__ cnt_all,
                                                 const int* __restrict__ base,
                                                 float* __restrict__ out) {
  const int e = blockIdx.z;
  const int cnt = cnt_all[e];
  const int m0 = blockIdx.y * 128;
  if (m0 >= cnt) return;
  __shared__ bf16 As[128 * 32];
  __shared__ bf16 Bs[128 * 32];
  __shared__ int toks[128];
  const int n0 = blockIdx.x * 128;  // H
  const int tid = threadIdx.x;
  const int wave = tid >> 6, lane = tid & 63;
  const int wr = wave >> 1, wc = wave & 1;
  const int quad = lane >> 4, l15 = lane & 15;

  if (tid < 128) {
    int s = m0 + tid;
    toks[tid] = (s < cnt) ? tok_list[e * T + s] : 0;
  }
  __syncthreads();

  const int c0 = (wave * 2 + 0) * 64 + lane;
  const int c1 = (wave * 2 + 1) * 64 + lane;
  const bf16* Ae = hbuf + (size_t)(base[e] + m0) * I;
  const bf16* a0 = Ae + (size_t)(c0 >> 2) * I + (c0 & 3) * 8;
  const bf16* a1 = Ae + (size_t)(c1 >> 2) * I + (c1 & 3) * 8;
  const bf16* Be = WdT + (size_t)e * H * I + (size_t)n0 * I;
  const bf16* b0 = Be + (size_t)(c0 >> 2) * I + (c0 & 3) * 8;
  const bf16* b1 = Be + (size_t)(c1 >> 2) * I + (c1 & 3) * 8;

  f32x4 acc[4][4];
  f32x4 zero = {0.f, 0.f, 0.f, 0.f};
#pragma unroll
  for (int j = 0; j < 4; ++j)
#pragma unroll
    for (int i = 0; i < 4; ++i) acc[j][i] = zero;

  for (int kt = 0; kt < I; kt += 32) {
    __syncthreads();
    gld16(a0 + kt, As + c0 * 8);
    gld16(a1 + kt, As + c1 * 8);
    gld16(b0 + kt, Bs + c0 * 8);
    gld16(b1 + kt, Bs + c1 * 8);
    __syncthreads();
    bf16x8 a[4];
#pragma unroll
    for (int i = 0; i < 4; ++i)
      a[i] = *(const bf16x8*)(As + (wr * 64 + i * 16 + l15) * 32 + quad * 8);
#pragma unroll
    for (int j = 0; j < 4; ++j) {
      bf16x8 b = *(const bf16x8*)(Bs + (wc * 64 + j * 16 + l15) * 32 + quad * 8);
#pragma unroll
      for (int i = 0; i < 4; ++i)
        acc[j][i] = __builtin_amdgcn_mfma_f32_16x16x32_bf16(a[i], b, acc[j][i], 0, 0, 0);
    }
  }
#pragma unroll
  for (int j = 0; j < 4; ++j)
#pragma unroll
    for (int i = 0; i < 4; ++i)
#pragma unroll
      for (int r = 0; r < 4; ++r) {
        int lrow = wr * 64 + i * 16 + quad * 4 + r;
        int ncol = n0 + wc * 64 + j * 16 + l15;
        atomicAdd(&out[(size_t)toks[lrow] * H + ncol], acc[j][i][r]);
      }
}

extern "C" void kernel_launch(void* const* d_in, const int* in_sizes, int n_in,
                              void* d_out, int out_size, void* d_ws, size_t ws_size,
                              hipStream_t stream) {
  const float* x    = (const float*)d_in[0];
  const float* Wg_s = (const float*)d_in[1];
  const float* Wu_s = (const float*)d_in[2];
  const float* Wd_s = (const float*)d_in[3];
  const float* Wg_r = (const float*)d_in[4];
  const float* Wu_r = (const float*)d_in[5];
  const float* Wd_r = (const float*)d_in[6];
  const float* Wr   = (const float*)d_in[7];
  const float* rb   = (const float*)d_in[8];
  float* out = (float*)d_out;

  char* p = (char*)d_ws;
  bf16* xb   = (bf16*)p;  p += (size_t)T * H * 2;
  bf16* WgT  = (bf16*)p;  p += (size_t)E_TOT * I * H * 2;
  bf16* WuT  = (bf16*)p;  p += (size_t)E_TOT * I * H * 2;
  bf16* hbuf = (bf16*)p;  p += (size_t)HROWS * I * 2;
  int*   tok_list = (int*)p;   p += (size_t)E_TOT * T * 4;
  float* wt_list  = (float*)p; p += (size_t)E_TOT * T * 4;
  int*   cnt_r    = (int*)p;   p += 256;
  int*   base     = (int*)p;   p += 256;
  int*   cnt_all  = (int*)p;   p += 256;
  bf16* WdT = WgT;  // reuse after gate/up GEMM has consumed WgT (stream-ordered)

  hipMemsetAsync(d_out, 0, (size_t)T * H * 4, stream);
  hipMemsetAsync(cnt_r, 0, 256, stream);
  cvt_x<<<(T * H) / 1024, 256, 0, stream>>>(x, xb, T * H);
  router<<<T / 4, 256, 0, stream>>>(x, Wr, rb, tok_list, wt_list, cnt_r);
  prefix<<<1, 64, 0, stream>>>(cnt_r, base, cnt_all);

  // gate/up weights: [H,I] -> [I,H] bf16
  transpose_cvt<<<dim3(I / 64, H / 64, E_SH), 256, 0, stream>>>(Wg_s, WgT, H, I, 1.f);
  transpose_cvt<<<dim3(I / 64, H / 64, E_RT), 256, 0, stream>>>(Wg_r, WgT + (size_t)E_SH * I * H, H, I, 1.f);
  transpose_cvt<<<dim3(I / 64, H / 64, E_SH), 256, 0, stream>>>(Wu_s, WuT, H, I, 1.f);
  transpose_cvt<<<dim3(I / 64, H / 64, E_RT), 256, 0, stream>>>(Wu_r, WuT + (size_t)E_SH * I * H, H, I, 1.f);

  gemm_gateup<<<dim3(I / 128, T / 128, E_TOT), 256, 0, stream>>>(
      xb, WgT, WuT, tok_list, wt_list, cnt_all, base, hbuf);

  // down weights: [I,H] -> [H,I] bf16; fold the shared-expert /2 into Wd_s
  transpose_cvt<<<dim3(H / 64, I / 64, E_SH), 256, 0, stream>>>(Wd_s, WdT, I, H, 0.5f);
  transpose_cvt<<<dim3(H / 64, I / 64, E_RT), 256, 0, stream>>>(Wd_r, WdT + (size_t)E_SH * H * I, I, H, 1.f);

  gemm_down<<<dim3(H / 128, T / 128, E_TOT), 256, 0, stream>>>(
      hbuf, WdT, tok_list, cnt_all, base, out);
}